// Round 12
// baseline (491.301 us; speedup 1.0000x reference)
//
#include <hip/hip_runtime.h>
#include <cstdint>

typedef __attribute__((ext_vector_type(8))) short bf16x8;
typedef __attribute__((ext_vector_type(4))) short bf16x4;
typedef __attribute__((ext_vector_type(4))) float f32x4;

#define S_LEN 4096
#define CDIM  640
#define NPROJ 5760

// K=16 bf16 MFMA (v_mfma_f32_16x16x16_bf16, gfx950-valid per ISA §10).
// Guarded so the HOST pass (which doesn't know amdgcn builtins) sees a stub.
__device__ __forceinline__ f32x4 mfma16(bf16x4 a, bf16x4 b, f32x4 c){
#if defined(__HIP_DEVICE_COMPILE__) && __HIP_DEVICE_COMPILE__
  return __builtin_amdgcn_mfma_f32_16x16x16bf16_1k(a, b, c, 0, 0, 0);
#else
  (void)a; (void)b;
  return c;
#endif
}

__device__ __forceinline__ unsigned short f2bf(float f){
  union { float f; uint32_t u; } v; v.f = f;
  uint32_t u = v.u;
  return (unsigned short)((u + 0x7fffu + ((u >> 16) & 1u)) >> 16);
}
__device__ __forceinline__ float b2f(unsigned short h){
  union { uint32_t u; float f; } v; v.u = ((uint32_t)h) << 16;
  return v.f;
}

// ---------------- labels: nearest-resize 512x512 -> 64x64, pack m | (im==0)<<8
__global__ void k_labels(const int* __restrict__ mask, const int* __restrict__ inp,
                         int* __restrict__ labels){
  int s = blockIdx.x * 256 + threadIdx.x;
  if (s >= S_LEN) return;
  int y = s >> 6, x = s & 63;
  int off = (y * 8) * 512 + x * 8;
  int m = mask[off] & 0xff;
  int o = (inp[off] == 0) ? 0x100 : 0;
  labels[s] = m | o;
}

// ---------------- bucket sort by label value (4 buckets)
__global__ void k_hist(const int* __restrict__ labels, int* __restrict__ boff, int* __restrict__ cnt){
  __shared__ int h[4];
  if (threadIdx.x < 4) h[threadIdx.x] = 0;
  __syncthreads();
  for (int s = threadIdx.x; s < S_LEN; s += 256) atomicAdd(&h[labels[s] & 3], 1);
  __syncthreads();
  if (threadIdx.x == 0){
    int a = 0;
    for (int c = 0; c < 4; c++){ boff[c] = a; a += h[c]; }
    boff[4] = a;
  }
  if (threadIdx.x < 4) cnt[threadIdx.x] = 0;
}

__global__ void k_perm(const int* __restrict__ labels, const int* __restrict__ boff,
                       int* __restrict__ cnt, int* __restrict__ perm,
                       int* __restrict__ inv, int* __restrict__ labP){
  int s = blockIdx.x * 256 + threadIdx.x;
  if (s >= S_LEN) return;
  int lab = labels[s];
  int c = lab & 3;
  int pos = boff[c] + atomicAdd(&cnt[c], 1);
  perm[pos] = s; inv[s] = pos; labP[pos] = lab;
}

// per 64-tile (attn80) and 128-tile (entity) key ranges; zero rowsum
__global__ void k_tiles(const int* __restrict__ labP, const int* __restrict__ boff,
                        int2* __restrict__ tr, int4* __restrict__ qtinfo,
                        float* __restrict__ rowsum){
  int t = threadIdx.x;
  __shared__ int nkt[32];
  if (t < 64){
    int c0 = labP[t * 64] & 3, c1 = labP[t * 64 + 63] & 3;
    tr[t] = make_int2(boff[c0] & ~63, (boff[c1 + 1] + 63) & ~63);
  }
  if (t < 32){
    int c0 = labP[t * 128] & 3, c1 = labP[t * 128 + 127] & 3;
    int lo = boff[c0] & ~127, hi = (boff[c1 + 1] + 127) & ~127;
    qtinfo[t].x = lo; qtinfo[t].y = hi; qtinfo[t].w = 0;
    nkt[t] = (hi - lo) >> 7;
  }
  __syncthreads();
  if (t == 0){
    int a = 0;
    for (int i = 0; i < 32; i++){ qtinfo[i].z = a; a += nkt[i]; }
  }
  for (int s = t; s < S_LEN; s += 256) rowsum[s] = 0.f;
}

// ---------------- f32 -> bf16 converts
__global__ void k_cvt_hs(const float* __restrict__ src, unsigned short* __restrict__ dst, int n){
  int idx = (blockIdx.x * 256 + threadIdx.x) * 4;
  if (idx >= n) return;
  float4 v = *(const float4*)(src + idx);
  ushort4 o;
  o.x = f2bf(v.x); o.y = f2bf(v.y); o.z = f2bf(v.z); o.w = f2bf(v.w);
  *(ushort4*)(dst + idx) = o;
}

struct WPtrs { const float* w[10]; };

__global__ void k_cvt_w(WPtrs p, unsigned short* __restrict__ dst){
  int e = (blockIdx.x * 256 + threadIdx.x) * 4;
  if (e >= 10 * 409600) return;
  int a = e / 409600, r = e % 409600;
  float sc = (a == 0 || a == 6) ? 0.11180339887498948f   // 1/sqrt(80)
           : (a == 3 ? 0.03952847075210474f : 1.0f);     // 1/sqrt(640)
  float4 v = *(const float4*)(p.w[a] + r);
  ushort4 o;
  o.x = f2bf(v.x * sc); o.y = f2bf(v.y * sc); o.z = f2bf(v.z * sc); o.w = f2bf(v.w * sc);
  *(ushort4*)(dst + e) = o;
}

// ---------------- 128x128 MFMA GEMM (BK=32): C[M,N] = A[M,K] * B[N,K]^T
template<int EPI>
__global__ __launch_bounds__(256) void k_gemm(const unsigned short* __restrict__ A,
                                              const unsigned short* __restrict__ B,
                                              int M, int N, int K, int ldc,
                                              const int* __restrict__ rowmap,
                                              unsigned short* __restrict__ Cb,
                                              float* __restrict__ Cf,
                                              const float* __restrict__ resid){
  __shared__ __align__(16) unsigned short As[128 * 40];
  __shared__ __align__(16) unsigned short Bs[128 * 40];
  int m0 = blockIdx.y * 128, n0 = blockIdx.x * 128;
  int tid = threadIdx.x;
  int wid = tid >> 6, lane = tid & 63;
  int quad = lane >> 4, l16 = lane & 15;
  int wm = (wid >> 1) * 64, wn = (wid & 1) * 64;
  f32x4 acc[4][4];
#pragma unroll
  for (int i = 0; i < 4; i++)
#pragma unroll
    for (int j = 0; j < 4; j++) acc[i][j] = f32x4{0.f, 0.f, 0.f, 0.f};

  for (int k0 = 0; k0 < K; k0 += 32){
    __syncthreads();
#pragma unroll
    for (int c = tid; c < 512; c += 256){
      int row = c >> 2, off = (c & 3) * 8;
      *(uint4*)(&As[row * 40 + off]) = *(const uint4*)(&A[(size_t)(m0 + row) * K + k0 + off]);
      *(uint4*)(&Bs[row * 40 + off]) = *(const uint4*)(&B[(size_t)(n0 + row) * K + k0 + off]);
    }
    __syncthreads();
    bf16x8 af[4], bfr[4];
#pragma unroll
    for (int t = 0; t < 4; t++){
      af[t]  = *(const bf16x8*)(&As[(wm + t * 16 + l16) * 40 + quad * 8]);
      bfr[t] = *(const bf16x8*)(&Bs[(wn + t * 16 + l16) * 40 + quad * 8]);
    }
#pragma unroll
    for (int mt = 0; mt < 4; mt++)
#pragma unroll
      for (int nt = 0; nt < 4; nt++)
        acc[mt][nt] = __builtin_amdgcn_mfma_f32_16x16x32_bf16(af[mt], bfr[nt], acc[mt][nt], 0, 0, 0);
  }
#pragma unroll
  for (int mt = 0; mt < 4; mt++)
#pragma unroll
    for (int nt = 0; nt < 4; nt++)
#pragma unroll
      for (int r = 0; r < 4; r++){
        int row = m0 + wm + mt * 16 + quad * 4 + r;
        int col = n0 + wn + nt * 16 + l16;
        float v = acc[mt][nt][r];
        if (EPI == 0){
          Cb[(size_t)rowmap[row] * ldc + col] = f2bf(v);
        } else {
          int ro = rowmap[row];
          Cf[(size_t)ro * ldc + col] = v + resid[(size_t)ro * ldc + col];
        }
      }
}

// ---------------- transpose the three V projections: vT[z][c][s] (permuted key index)
__global__ void k_transpose_v(const unsigned short* __restrict__ proj, unsigned short* __restrict__ vT){
  __shared__ unsigned short T[64][65];
  int z = blockIdx.z;
  int s0 = blockIdx.x * 64, c0 = blockIdx.y * 64;
  int colbase = 1280 + z * 1920 + c0;   // v:1280  v_e:3200  v_o:5120
  unsigned short* dst = vT + (size_t)z * CDIM * S_LEN;
  int tid = threadIdx.x;
  for (int i = tid; i < 64 * 64; i += 256){
    int r = i >> 6, c = i & 63;
    T[r][c] = proj[(size_t)(s0 + r) * NPROJ + colbase + c];
  }
  __syncthreads();
  for (int i = tid; i < 64 * 64; i += 256){
    int c = i >> 6, r = i & 63;
    dst[(size_t)(c0 + c) * S_LEN + s0 + r] = T[r][c];
  }
}

// ---------------- flash attention, d=80, z=0: orig, z=1: outside
// v9: R10 compute structure (2 Q-sets/wave, KP=84/VP=76, no prefetch) at
// 128 threads / 64-query tiles -> grid 2048 blocks, ~6 blocks/CU for TLP.
#define KP 84
#define VP 76
__global__ __launch_bounds__(128, 2) void k_attn80(const unsigned short* __restrict__ proj,
                                                   const unsigned short* __restrict__ vT,
                                                   const int* __restrict__ labP,
                                                   const int2* __restrict__ tileRange,
                                                   unsigned short* __restrict__ outP){
  __shared__ __align__(16) unsigned short Ks[64 * KP];
  __shared__ __align__(16) unsigned short Vt[80 * VP];
  __shared__ __align__(16) int labk[64];
  int tid = threadIdx.x, wid = tid >> 6, lane = tid & 63;
  int quad = lane >> 4, l16 = lane & 15;
  int q0 = blockIdx.x * 64;
  int h  = blockIdx.y;
  bool OUTSIDE = (blockIdx.z == 1);
  int qc = (OUTSIDE ? 3840 : 0) + h * 80;
  int kc = (OUTSIDE ? 4480 : 640) + h * 80;
  const unsigned short* vTb = vT + (size_t)(OUTSIDE ? 2 : 0) * CDIM * S_LEN;
  int2 range = tileRange[blockIdx.x];
  int t0 = range.x >> 6, t1 = range.y >> 6;

  // two query sets per wave (B-operand layout: lane n=l16 is the query, k=quad*4+j)
  int qrow0 = q0 + wid * 32 + l16;
  int qrow1 = qrow0 + 16;
  bf16x4 qf0[5], qf1[5];
#pragma unroll
  for (int dc = 0; dc < 5; dc++){
    qf0[dc] = *(const bf16x4*)&proj[(size_t)qrow0 * NPROJ + qc + dc * 16 + quad * 4];
    qf1[dc] = *(const bf16x4*)&proj[(size_t)qrow1 * NPROJ + qc + dc * 16 + quad * 4];
  }
  int lq0 = labP[qrow0] & 0xff, lq1 = labP[qrow1] & 0xff;

  float lp0 = 0.f, lp1 = 0.f;
  f32x4 Oc0[5], Oc1[5];
#pragma unroll
  for (int t = 0; t < 5; t++){ Oc0[t] = f32x4{0.f,0.f,0.f,0.f}; Oc1[t] = f32x4{0.f,0.f,0.f,0.f}; }

  for (int kt = t0; kt < t1; kt++){
    int key0 = kt * 64;
    __syncthreads();                       // prior tile's Ks/Vt reads done
    // transient staging: 640 uint4 of K and V each, 5+5 loads per thread
#pragma unroll
    for (int u = 0; u < 5; u++){
      int c = tid + u * 128;
      int krow = c / 10, koff = (c % 10) * 8;
      int vrow = c >> 3, voff = (c & 7) * 8;
      *(uint4*)&Ks[krow * KP + koff] =
        *(const uint4*)&proj[(size_t)(key0 + krow) * NPROJ + kc + koff];
      *(uint4*)&Vt[vrow * VP + voff] =
        *(const uint4*)&vTb[(size_t)(h * 80 + vrow) * S_LEN + key0 + voff];
    }
    if (tid < 64) labk[tid] = labP[key0 + tid];
    __syncthreads();

#pragma unroll
    for (int kg = 0; kg < 4; kg++){
      // S^T(16 keys x 16 queries) = K * Q^T, two query sets share kf
      f32x4 sa0 = f32x4{0.f,0.f,0.f,0.f}, sa1 = f32x4{0.f,0.f,0.f,0.f};
#pragma unroll
      for (int dc = 0; dc < 5; dc++){
        bf16x4 kf = *(const bf16x4*)&Ks[(kg * 16 + l16) * KP + dc * 16 + quad * 4];
        sa0 = mfma16(kf, qf0[dc], sa0);
        sa1 = mfma16(kf, qf1[dc], sa1);
      }
      int4 lk4 = *(const int4*)&labk[kg * 16 + quad * 4];
      bool m0 = !OUTSIDE || (lk4.x & 0x100), m1 = !OUTSIDE || (lk4.y & 0x100);
      bool m2 = !OUTSIDE || (lk4.z & 0x100), m3 = !OUTSIDE || (lk4.w & 0x100);
      int k0l = lk4.x & 0xff, k1l = lk4.y & 0xff, k2l = lk4.z & 0xff, k3l = lk4.w & 0xff;
      bf16x4 pf0, pf1;
      {
        float p0 = (k0l == lq0 && m0) ? __expf(sa0[0]) : 0.f;
        float p1 = (k1l == lq0 && m1) ? __expf(sa0[1]) : 0.f;
        float p2 = (k2l == lq0 && m2) ? __expf(sa0[2]) : 0.f;
        float p3 = (k3l == lq0 && m3) ? __expf(sa0[3]) : 0.f;
        lp0 += (p0 + p1) + (p2 + p3);
        pf0[0] = (short)f2bf(p0); pf0[1] = (short)f2bf(p1);
        pf0[2] = (short)f2bf(p2); pf0[3] = (short)f2bf(p3);
      }
      {
        float p0 = (k0l == lq1 && m0) ? __expf(sa1[0]) : 0.f;
        float p1 = (k1l == lq1 && m1) ? __expf(sa1[1]) : 0.f;
        float p2 = (k2l == lq1 && m2) ? __expf(sa1[2]) : 0.f;
        float p3 = (k3l == lq1 && m3) ? __expf(sa1[3]) : 0.f;
        lp1 += (p0 + p1) + (p2 + p3);
        pf1[0] = (short)f2bf(p0); pf1[1] = (short)f2bf(p1);
        pf1[2] = (short)f2bf(p2); pf1[3] = (short)f2bf(p3);
      }
      // O^T += V^T * P^T, two query sets share vf
#pragma unroll
      for (int dt = 0; dt < 5; dt++){
        bf16x4 vf = *(const bf16x4*)&Vt[(dt * 16 + l16) * VP + kg * 16 + quad * 4];
        Oc0[dt] = mfma16(vf, pf0, Oc0[dt]);
        Oc1[dt] = mfma16(vf, pf1, Oc1[dt]);
      }
    }
  }
  // row-sums: reduce across quads (same l16)
  lp0 += __shfl_xor(lp0, 16); lp0 += __shfl_xor(lp0, 32);
  lp1 += __shfl_xor(lp1, 16); lp1 += __shfl_xor(lp1, 32);
  float iL0 = 1.f / lp0, iL1 = 1.f / lp1;
  unsigned short* dst = outP + (size_t)blockIdx.z * S_LEN * CDIM;
#pragma unroll
  for (int dt = 0; dt < 5; dt++){
    ushort4 o;
    o.x = f2bf(Oc0[dt][0] * iL0); o.y = f2bf(Oc0[dt][1] * iL0);
    o.z = f2bf(Oc0[dt][2] * iL0); o.w = f2bf(Oc0[dt][3] * iL0);
    *(ushort4*)&dst[(size_t)qrow0 * CDIM + h * 80 + dt * 16 + quad * 4] = o;
    o.x = f2bf(Oc1[dt][0] * iL1); o.y = f2bf(Oc1[dt][1] * iL1);
    o.z = f2bf(Oc1[dt][2] * iL1); o.w = f2bf(Oc1[dt][3] * iL1);
    *(ushort4*)&dst[(size_t)qrow1 * CDIM + h * 80 + dt * 16 + quad * 4] = o;
  }
}

// ---------------- entity E1: P = exp(Q_e K_e^T) per (qtile, ktile), bf16, + rowsums
__global__ __launch_bounds__(256) void k_ent_qk(const unsigned short* __restrict__ proj,
                                                const int* __restrict__ labP,
                                                const int4* __restrict__ qtinfo,
                                                unsigned short* __restrict__ Sbuf,
                                                float* __restrict__ rowsum){
  int qt = blockIdx.y;
  int4 qi = qtinfo[qt];
  int nkt = (qi.y - qi.x) >> 7;
  if ((int)blockIdx.x >= nkt) return;
  int m0 = qt * 128, n0 = qi.x + blockIdx.x * 128;
  __shared__ __align__(16) unsigned short As[128 * 40];
  __shared__ __align__(16) unsigned short Bs[128 * 40];
  __shared__ int lQ[128], lK[128];
  int tid = threadIdx.x, wid = tid >> 6, lane = tid & 63;
  int quad = lane >> 4, l16 = lane & 15;
  int wm = (wid >> 1) * 64, wn = (wid & 1) * 64;
  if (tid < 128) lQ[tid] = labP[m0 + tid] & 0xff;
  else           lK[tid - 128] = labP[n0 + tid - 128] & 0xff;
  f32x4 acc[4][4];
#pragma unroll
  for (int i = 0; i < 4; i++)
#pragma unroll
    for (int j = 0; j < 4; j++) acc[i][j] = f32x4{0.f, 0.f, 0.f, 0.f};

  for (int k0 = 0; k0 < 640; k0 += 32){
    __syncthreads();
#pragma unroll
    for (int c = tid; c < 512; c += 256){
      int row = c >> 2, off = (c & 3) * 8;
      *(uint4*)(&As[row * 40 + off]) = *(const uint4*)(&proj[(size_t)(m0 + row) * NPROJ + 1920 + k0 + off]);
      *(uint4*)(&Bs[row * 40 + off]) = *(const uint4*)(&proj[(size_t)(n0 + row) * NPROJ + 2560 + k0 + off]);
    }
    __syncthreads();
    bf16x8 af[4], bfr[4];
#pragma unroll
    for (int t = 0; t < 4; t++){
      af[t]  = *(const bf16x8*)(&As[(wm + t * 16 + l16) * 40 + quad * 8]);
      bfr[t] = *(const bf16x8*)(&Bs[(wn + t * 16 + l16) * 40 + quad * 8]);
    }
#pragma unroll
    for (int mt = 0; mt < 4; mt++)
#pragma unroll
      for (int nt = 0; nt < 4; nt++)
        acc[mt][nt] = __builtin_amdgcn_mfma_f32_16x16x32_bf16(af[mt], bfr[nt], acc[mt][nt], 0, 0, 0);
  }
  unsigned short* St = Sbuf + ((size_t)(qi.z + blockIdx.x)) * 16384;
#pragma unroll
  for (int mt = 0; mt < 4; mt++)
#pragma unroll
    for (int r = 0; r < 4; r++){
      int lrow = wm + mt * 16 + quad * 4 + r;
      int myq = lQ[lrow];
      float psum = 0.f;
#pragma unroll
      for (int nt = 0; nt < 4; nt++){
        int lcol = wn + nt * 16 + l16;
        float p = (myq == lK[lcol]) ? __expf(acc[mt][nt][r]) : 0.f;
        St[lrow * 128 + lcol] = f2bf(p);
        psum += p;
      }
#pragma unroll
      for (int m = 1; m < 16; m <<= 1) psum += __shfl_xor(psum, m);
      if (l16 == 0) atomicAdd(&rowsum[m0 + lrow], psum);
    }
}

// ---------------- entity E2: attnS = bf16( P·V_e / rowsum + plane0 + plane1 )
__global__ __launch_bounds__(256) void k_ent_pv(const unsigned short* __restrict__ Sbuf,
                                                const unsigned short* __restrict__ veT,
                                                const int4* __restrict__ qtinfo,
                                                const float* __restrict__ rowsum,
                                                const unsigned short* __restrict__ planes,
                                                unsigned short* __restrict__ attnS){
  int qt = blockIdx.y, d0 = blockIdx.x * 128;
  int4 qi = qtinfo[qt];
  int m0 = qt * 128;
  int nk = qi.y - qi.x;
  __shared__ __align__(16) unsigned short As[128 * 40];
  __shared__ __align__(16) unsigned short Bs[128 * 40];
  int tid = threadIdx.x, wid = tid >> 6, lane = tid & 63;
  int quad = lane >> 4, l16 = lane & 15;
  int wm = (wid >> 1) * 64, wn = (wid & 1) * 64;
  f32x4 acc[4][4];
#pragma unroll
  for (int i = 0; i < 4; i++)
#pragma unroll
    for (int j = 0; j < 4; j++) acc[i][j] = f32x4{0.f, 0.f, 0.f, 0.f};

  for (int kk = 0; kk < nk; kk += 32){
    const unsigned short* St = Sbuf + ((size_t)(qi.z + (kk >> 7))) * 16384;
    int kloc = kk & 127;
    __syncthreads();
#pragma unroll
    for (int c = tid; c < 512; c += 256){
      int row = c >> 2, off = (c & 3) * 8;
      *(uint4*)(&As[row * 40 + off]) = *(const uint4*)(&St[row * 128 + kloc + off]);
      *(uint4*)(&Bs[row * 40 + off]) = *(const uint4*)(&veT[(size_t)(d0 + row) * S_LEN + qi.x + kk + off]);
    }
    __syncthreads();
    bf16x8 af[4], bfr[4];
#pragma unroll
    for (int t = 0; t < 4; t++){
      af[t]  = *(const bf16x8*)(&As[(wm + t * 16 + l16) * 40 + quad * 8]);
      bfr[t] = *(const bf16x8*)(&Bs[(wn + t * 16 + l16) * 40 + quad * 8]);
    }
#pragma unroll
    for (int mt = 0; mt < 4; mt++)
#pragma unroll
      for (int nt = 0; nt < 4; nt++)
        acc[mt][nt] = __builtin_amdgcn_mfma_f32_16x16x32_bf16(af[mt], bfr[nt], acc[mt][nt], 0, 0, 0);
  }
#pragma unroll
  for (int mt = 0; mt < 4; mt++)
#pragma unroll
    for (int r = 0; r < 4; r++){
      int row = m0 + wm + mt * 16 + quad * 4 + r;
      float invL = 1.f / rowsum[row];
#pragma unroll
      for (int nt = 0; nt < 4; nt++){
        int col = d0 + wn + nt * 16 + l16;
        size_t idx = (size_t)row * CDIM + col;
        float v = acc[mt][nt][r] * invL + b2f(planes[idx]) + b2f(planes[(size_t)S_LEN * CDIM + idx]);
        attnS[idx] = f2bf(v);
      }
    }
}

extern "C" void kernel_launch(void* const* d_in, const int* in_sizes, int n_in,
                              void* d_out, int out_size, void* d_ws, size_t ws_size,
                              hipStream_t stream){
  const float* hs  = (const float*)d_in[0];
  const int* mask  = (const int*)d_in[1];
  const int* inp   = (const int*)d_in[2];
  char* ws = (char*)d_ws;
  int*            labels  = (int*)(ws + 0);
  int*            boff    = (int*)(ws + 16384);
  int*            cnt     = (int*)(ws + 16640);
  int*            perm    = (int*)(ws + 16896);
  int*            inv     = (int*)(ws + 33280);
  int*            labP    = (int*)(ws + 49664);
  int2*           tileR   = (int2*)(ws + 66048);
  int4*           qtinfo  = (int4*)(ws + 66560);
  float*          rowsum  = (float*)(ws + 67072);
  unsigned short* hsb     = (unsigned short*)(ws + 131072);
  unsigned short* Wall    = (unsigned short*)(ws + 5373952);
  unsigned short* proj    = (unsigned short*)(ws + 13565952);
  unsigned short* vT      = (unsigned short*)(ws + 60751872);
  unsigned short* planes  = (unsigned short*)(ws + 76480512);   // 2 bf16 planes = 10.5 MB
  unsigned short* Sbuf    = (unsigned short*)(ws + 86966272);   // up to 1024 tiles * 32 KB
  unsigned short* attnS   = (unsigned short*)(ws + 120520704);
  unsigned short* Wob     = Wall + 9 * 409600;

  k_labels<<<16, 256, 0, stream>>>(mask, inp, labels);
  k_hist<<<1, 256, 0, stream>>>(labels, boff, cnt);
  k_perm<<<16, 256, 0, stream>>>(labels, boff, cnt, perm, inv, labP);
  k_tiles<<<1, 256, 0, stream>>>(labP, boff, tileR, qtinfo, rowsum);
  k_cvt_hs<<<(S_LEN * CDIM / 4 + 255) / 256, 256, 0, stream>>>(hs, hsb, S_LEN * CDIM);
  WPtrs wp;
  for (int i = 0; i < 10; i++) wp.w[i] = (const float*)d_in[3 + i];
  k_cvt_w<<<(10 * 409600 / 4 + 255) / 256, 256, 0, stream>>>(wp, Wall);

  // all 9 projections in one GEMM, rows scattered into bucket-permuted order
  k_gemm<0><<<dim3(45, 32), 256, 0, stream>>>(hsb, Wall, S_LEN, NPROJ, CDIM, NPROJ,
                                              inv, proj, nullptr, nullptr);
  k_transpose_v<<<dim3(64, 10, 3), 256, 0, stream>>>(proj, vT);

  // branches 1+3: z=0 orig (q,k,v), z=1 outside (q_o,k_o,v_o) with im==0 key gate
  k_attn80<<<dim3(64, 8, 2), 128, 0, stream>>>(proj, vT, labP, tileR, planes);

  // branch 2 (entity, d=640): GEMM-ified, P materialized bf16 per bucket
  k_ent_qk<<<dim3(32, 32), 256, 0, stream>>>(proj, labP, qtinfo, Sbuf, rowsum);
  k_ent_pv<<<dim3(5, 32), 256, 0, stream>>>(Sbuf, vT + (size_t)1 * CDIM * S_LEN,
                                            qtinfo, rowsum, planes, attnS);

  // out = attnS @ Wo^T + residual, un-permuted via perm in the epilogue
  k_gemm<1><<<dim3(5, 32), 256, 0, stream>>>(attnS, Wob, S_LEN, CDIM, CDIM, CDIM,
                                             perm, nullptr, (float*)d_out, hs);
}

// Round 13
// 414.903 us; speedup vs baseline: 1.1841x; 1.1841x over previous
//
#include <hip/hip_runtime.h>
#include <cstdint>

typedef __attribute__((ext_vector_type(8))) short bf16x8;
typedef __attribute__((ext_vector_type(4))) short bf16x4;
typedef __attribute__((ext_vector_type(4))) float f32x4;

#define S_LEN 4096
#define CDIM  640
#define NPROJ 5760

// K=16 bf16 MFMA (v_mfma_f32_16x16x16_bf16, gfx950-valid per ISA §10).
__device__ __forceinline__ f32x4 mfma16(bf16x4 a, bf16x4 b, f32x4 c){
#if defined(__HIP_DEVICE_COMPILE__) && __HIP_DEVICE_COMPILE__
  return __builtin_amdgcn_mfma_f32_16x16x16bf16_1k(a, b, c, 0, 0, 0);
#else
  (void)a; (void)b;
  return c;
#endif
}

// async global->LDS, 16B per lane; LDS dest must be wave-uniform base + lane*16
__device__ __forceinline__ void gload_lds(const unsigned short* g, unsigned short* l){
#if defined(__HIP_DEVICE_COMPILE__) && __HIP_DEVICE_COMPILE__
  __builtin_amdgcn_global_load_lds((const __attribute__((address_space(1))) unsigned int*)g,
                                   (__attribute__((address_space(3))) unsigned int*)l, 16, 0, 0);
#else
  (void)g; (void)l;
#endif
}

__device__ __forceinline__ unsigned short f2bf(float f){
  union { float f; uint32_t u; } v; v.f = f;
  uint32_t u = v.u;
  return (unsigned short)((u + 0x7fffu + ((u >> 16) & 1u)) >> 16);
}
__device__ __forceinline__ float b2f(unsigned short h){
  union { uint32_t u; float f; } v; v.u = ((uint32_t)h) << 16;
  return v.f;
}

// ---------------- labels: nearest-resize 512x512 -> 64x64, pack m | (im==0)<<8
__global__ void k_labels(const int* __restrict__ mask, const int* __restrict__ inp,
                         int* __restrict__ labels){
  int s = blockIdx.x * 256 + threadIdx.x;
  if (s >= S_LEN) return;
  int y = s >> 6, x = s & 63;
  int off = (y * 8) * 512 + x * 8;
  int m = mask[off] & 0xff;
  int o = (inp[off] == 0) ? 0x100 : 0;
  labels[s] = m | o;
}

// ---------------- bucket sort by label value (4 buckets)
__global__ void k_hist(const int* __restrict__ labels, int* __restrict__ boff, int* __restrict__ cnt){
  __shared__ int h[4];
  if (threadIdx.x < 4) h[threadIdx.x] = 0;
  __syncthreads();
  for (int s = threadIdx.x; s < S_LEN; s += 256) atomicAdd(&h[labels[s] & 3], 1);
  __syncthreads();
  if (threadIdx.x == 0){
    int a = 0;
    for (int c = 0; c < 4; c++){ boff[c] = a; a += h[c]; }
    boff[4] = a;
  }
  if (threadIdx.x < 4) cnt[threadIdx.x] = 0;
}

__global__ void k_perm(const int* __restrict__ labels, const int* __restrict__ boff,
                       int* __restrict__ cnt, int* __restrict__ perm,
                       int* __restrict__ inv, int* __restrict__ labP){
  int s = blockIdx.x * 256 + threadIdx.x;
  if (s >= S_LEN) return;
  int lab = labels[s];
  int c = lab & 3;
  int pos = boff[c] + atomicAdd(&cnt[c], 1);
  perm[pos] = s; inv[s] = pos; labP[pos] = lab;
}

// per 128-tile key ranges (shared by attn80 and entity); zero rowsum
__global__ void k_tiles(const int* __restrict__ labP, const int* __restrict__ boff,
                        int4* __restrict__ qtinfo, float* __restrict__ rowsum){
  int t = threadIdx.x;
  __shared__ int nkt[32];
  if (t < 32){
    int c0 = labP[t * 128] & 3, c1 = labP[t * 128 + 127] & 3;
    int lo = boff[c0] & ~127, hi = (boff[c1 + 1] + 127) & ~127;
    qtinfo[t].x = lo; qtinfo[t].y = hi; qtinfo[t].w = 0;
    nkt[t] = (hi - lo) >> 7;
  }
  __syncthreads();
  if (t == 0){
    int a = 0;
    for (int i = 0; i < 32; i++){ qtinfo[i].z = a; a += nkt[i]; }
  }
  for (int s = t; s < S_LEN; s += 256) rowsum[s] = 0.f;
}

// ---------------- f32 -> bf16 converts
__global__ void k_cvt_hs(const float* __restrict__ src, unsigned short* __restrict__ dst, int n){
  int idx = (blockIdx.x * 256 + threadIdx.x) * 4;
  if (idx >= n) return;
  float4 v = *(const float4*)(src + idx);
  ushort4 o;
  o.x = f2bf(v.x); o.y = f2bf(v.y); o.z = f2bf(v.z); o.w = f2bf(v.w);
  *(ushort4*)(dst + idx) = o;
}

struct WPtrs { const float* w[10]; };

__global__ void k_cvt_w(WPtrs p, unsigned short* __restrict__ dst){
  int e = (blockIdx.x * 256 + threadIdx.x) * 4;
  if (e >= 10 * 409600) return;
  int a = e / 409600, r = e % 409600;
  float sc = (a == 0 || a == 6) ? 0.11180339887498948f   // 1/sqrt(80)
           : (a == 3 ? 0.03952847075210474f : 1.0f);     // 1/sqrt(640)
  float4 v = *(const float4*)(p.w[a] + r);
  ushort4 o;
  o.x = f2bf(v.x * sc); o.y = f2bf(v.y * sc); o.z = f2bf(v.z * sc); o.w = f2bf(v.w * sc);
  *(ushort4*)(dst + e) = o;
}

// ---------------- 128x128 MFMA GEMM (BK=32, global_load_lds staging, pitch 32)
template<int EPI>
__global__ __launch_bounds__(256) void k_gemm(const unsigned short* __restrict__ A,
                                              const unsigned short* __restrict__ B,
                                              int M, int N, int K, int ldc,
                                              const int* __restrict__ rowmap,
                                              unsigned short* __restrict__ Cb,
                                              float* __restrict__ Cf,
                                              const float* __restrict__ resid){
  __shared__ __align__(16) unsigned short As[128 * 32];
  __shared__ __align__(16) unsigned short Bs[128 * 32];
  int m0 = blockIdx.y * 128, n0 = blockIdx.x * 128;
  int tid = threadIdx.x;
  int wid = tid >> 6, lane = tid & 63;
  int quad = lane >> 4, l16 = lane & 15;
  int wm = (wid >> 1) * 64, wn = (wid & 1) * 64;
  f32x4 acc[4][4];
#pragma unroll
  for (int i = 0; i < 4; i++)
#pragma unroll
    for (int j = 0; j < 4; j++) acc[i][j] = f32x4{0.f, 0.f, 0.f, 0.f};

  for (int k0 = 0; k0 < K; k0 += 32){
    __syncthreads();
#pragma unroll
    for (int u = 0; u < 2; u++){
      int c = tid + u * 256;
      int row = c >> 2, off = (c & 3) * 8;
      gload_lds(&A[(size_t)(m0 + row) * K + k0 + off], &As[c * 8]);
      gload_lds(&B[(size_t)(n0 + row) * K + k0 + off], &Bs[c * 8]);
    }
    __syncthreads();
    bf16x8 af[4], bfr[4];
#pragma unroll
    for (int t = 0; t < 4; t++){
      af[t]  = *(const bf16x8*)(&As[(wm + t * 16 + l16) * 32 + quad * 8]);
      bfr[t] = *(const bf16x8*)(&Bs[(wn + t * 16 + l16) * 32 + quad * 8]);
    }
#pragma unroll
    for (int mt = 0; mt < 4; mt++)
#pragma unroll
      for (int nt = 0; nt < 4; nt++)
        acc[mt][nt] = __builtin_amdgcn_mfma_f32_16x16x32_bf16(af[mt], bfr[nt], acc[mt][nt], 0, 0, 0);
  }
#pragma unroll
  for (int mt = 0; mt < 4; mt++)
#pragma unroll
    for (int nt = 0; nt < 4; nt++)
#pragma unroll
      for (int r = 0; r < 4; r++){
        int row = m0 + wm + mt * 16 + quad * 4 + r;
        int col = n0 + wn + nt * 16 + l16;
        float v = acc[mt][nt][r];
        if (EPI == 0){
          Cb[(size_t)rowmap[row] * ldc + col] = f2bf(v);
        } else {
          int ro = rowmap[row];
          Cf[(size_t)ro * ldc + col] = v + resid[(size_t)ro * ldc + col];
        }
      }
}

// ---------------- transpose the three V projections: vT[z][c][s] (permuted key index)
__global__ void k_transpose_v(const unsigned short* __restrict__ proj, unsigned short* __restrict__ vT){
  __shared__ unsigned short T[64][65];
  int z = blockIdx.z;
  int s0 = blockIdx.x * 64, c0 = blockIdx.y * 64;
  int colbase = 1280 + z * 1920 + c0;   // v:1280  v_e:3200  v_o:5120
  unsigned short* dst = vT + (size_t)z * CDIM * S_LEN;
  int tid = threadIdx.x;
  for (int i = tid; i < 64 * 64; i += 256){
    int r = i >> 6, c = i & 63;
    T[r][c] = proj[(size_t)(s0 + r) * NPROJ + colbase + c];
  }
  __syncthreads();
  for (int i = tid; i < 64 * 64; i += 256){
    int c = i >> 6, r = i & 63;
    dst[(size_t)(c0 + c) * S_LEN + s0 + r] = T[r][c];
  }
}

// ---------------- flash attention, d=80, z=0: orig, z=1: outside
// R10 configuration (proven 124 us): 128-query tiles, 2 Q-sets/wave,
// KP=84/VP=76 (2-way banks), transient staging, launch_bounds(256,2).
#define KP 84
#define VP 76
__global__ __launch_bounds__(256, 2) void k_attn80(const unsigned short* __restrict__ proj,
                                                   const unsigned short* __restrict__ vT,
                                                   const int* __restrict__ labP,
                                                   const int4* __restrict__ qtinfo,
                                                   unsigned short* __restrict__ outP){
  __shared__ __align__(16) unsigned short Ks[64 * KP];
  __shared__ __align__(16) unsigned short Vt[80 * VP];
  __shared__ __align__(16) int labk[64];
  int tid = threadIdx.x, wid = tid >> 6, lane = tid & 63;
  int quad = lane >> 4, l16 = lane & 15;
  int q0 = blockIdx.x * 128;
  int h  = blockIdx.y;
  bool OUTSIDE = (blockIdx.z == 1);
  int qc = (OUTSIDE ? 3840 : 0) + h * 80;
  int kc = (OUTSIDE ? 4480 : 640) + h * 80;
  const unsigned short* vTb = vT + (size_t)(OUTSIDE ? 2 : 0) * CDIM * S_LEN;
  int4 qi = qtinfo[blockIdx.x];
  int t0 = qi.x >> 6, t1 = qi.y >> 6;

  // two query sets per wave (B-operand layout: lane n=l16 is the query, k=quad*4+j)
  int qrow0 = q0 + wid * 32 + l16;
  int qrow1 = qrow0 + 16;
  bf16x4 qf0[5], qf1[5];
#pragma unroll
  for (int dc = 0; dc < 5; dc++){
    qf0[dc] = *(const bf16x4*)&proj[(size_t)qrow0 * NPROJ + qc + dc * 16 + quad * 4];
    qf1[dc] = *(const bf16x4*)&proj[(size_t)qrow1 * NPROJ + qc + dc * 16 + quad * 4];
  }
  int lq0 = labP[qrow0] & 0xff, lq1 = labP[qrow1] & 0xff;

  float lp0 = 0.f, lp1 = 0.f;
  f32x4 Oc0[5], Oc1[5];
#pragma unroll
  for (int t = 0; t < 5; t++){ Oc0[t] = f32x4{0.f,0.f,0.f,0.f}; Oc1[t] = f32x4{0.f,0.f,0.f,0.f}; }

  for (int kt = t0; kt < t1; kt++){
    int key0 = kt * 64;
    __syncthreads();                       // prior tile's Ks/Vt reads done
    // transient staging: coordinates recomputed inline, no long-lived registers
#pragma unroll
    for (int u = 0; u < 3; u++){
      int c = tid + u * 256;
      if (c < 640){
        int krow = c / 10, koff = (c % 10) * 8;
        int vrow = c >> 3, voff = (c & 7) * 8;
        *(uint4*)&Ks[krow * KP + koff] =
          *(const uint4*)&proj[(size_t)(key0 + krow) * NPROJ + kc + koff];
        *(uint4*)&Vt[vrow * VP + voff] =
          *(const uint4*)&vTb[(size_t)(h * 80 + vrow) * S_LEN + key0 + voff];
      }
    }
    if (tid < 64) labk[tid] = labP[key0 + tid];
    __syncthreads();

#pragma unroll
    for (int kg = 0; kg < 4; kg++){
      // S^T(16 keys x 16 queries) = K * Q^T, two query sets share kf
      f32x4 sa0 = f32x4{0.f,0.f,0.f,0.f}, sa1 = f32x4{0.f,0.f,0.f,0.f};
#pragma unroll
      for (int dc = 0; dc < 5; dc++){
        bf16x4 kf = *(const bf16x4*)&Ks[(kg * 16 + l16) * KP + dc * 16 + quad * 4];
        sa0 = mfma16(kf, qf0[dc], sa0);
        sa1 = mfma16(kf, qf1[dc], sa1);
      }
      int4 lk4 = *(const int4*)&labk[kg * 16 + quad * 4];
      bool m0 = !OUTSIDE || (lk4.x & 0x100), m1 = !OUTSIDE || (lk4.y & 0x100);
      bool m2 = !OUTSIDE || (lk4.z & 0x100), m3 = !OUTSIDE || (lk4.w & 0x100);
      int k0l = lk4.x & 0xff, k1l = lk4.y & 0xff, k2l = lk4.z & 0xff, k3l = lk4.w & 0xff;
      bf16x4 pf0, pf1;
      {
        float p0 = (k0l == lq0 && m0) ? __expf(sa0[0]) : 0.f;
        float p1 = (k1l == lq0 && m1) ? __expf(sa0[1]) : 0.f;
        float p2 = (k2l == lq0 && m2) ? __expf(sa0[2]) : 0.f;
        float p3 = (k3l == lq0 && m3) ? __expf(sa0[3]) : 0.f;
        lp0 += (p0 + p1) + (p2 + p3);
        pf0[0] = (short)f2bf(p0); pf0[1] = (short)f2bf(p1);
        pf0[2] = (short)f2bf(p2); pf0[3] = (short)f2bf(p3);
      }
      {
        float p0 = (k0l == lq1 && m0) ? __expf(sa1[0]) : 0.f;
        float p1 = (k1l == lq1 && m1) ? __expf(sa1[1]) : 0.f;
        float p2 = (k2l == lq1 && m2) ? __expf(sa1[2]) : 0.f;
        float p3 = (k3l == lq1 && m3) ? __expf(sa1[3]) : 0.f;
        lp1 += (p0 + p1) + (p2 + p3);
        pf1[0] = (short)f2bf(p0); pf1[1] = (short)f2bf(p1);
        pf1[2] = (short)f2bf(p2); pf1[3] = (short)f2bf(p3);
      }
      // O^T += V^T * P^T, two query sets share vf
#pragma unroll
      for (int dt = 0; dt < 5; dt++){
        bf16x4 vf = *(const bf16x4*)&Vt[(dt * 16 + l16) * VP + kg * 16 + quad * 4];
        Oc0[dt] = mfma16(vf, pf0, Oc0[dt]);
        Oc1[dt] = mfma16(vf, pf1, Oc1[dt]);
      }
    }
  }
  // row-sums: reduce across quads (same l16)
  lp0 += __shfl_xor(lp0, 16); lp0 += __shfl_xor(lp0, 32);
  lp1 += __shfl_xor(lp1, 16); lp1 += __shfl_xor(lp1, 32);
  float iL0 = 1.f / lp0, iL1 = 1.f / lp1;
  unsigned short* dst = outP + (size_t)blockIdx.z * S_LEN * CDIM;
#pragma unroll
  for (int dt = 0; dt < 5; dt++){
    ushort4 o;
    o.x = f2bf(Oc0[dt][0] * iL0); o.y = f2bf(Oc0[dt][1] * iL0);
    o.z = f2bf(Oc0[dt][2] * iL0); o.w = f2bf(Oc0[dt][3] * iL0);
    *(ushort4*)&dst[(size_t)qrow0 * CDIM + h * 80 + dt * 16 + quad * 4] = o;
    o.x = f2bf(Oc1[dt][0] * iL1); o.y = f2bf(Oc1[dt][1] * iL1);
    o.z = f2bf(Oc1[dt][2] * iL1); o.w = f2bf(Oc1[dt][3] * iL1);
    *(ushort4*)&dst[(size_t)qrow1 * CDIM + h * 80 + dt * 16 + quad * 4] = o;
  }
}

// ---------------- entity E1: P = exp(Q_e K_e^T) per (qtile, ktile), bf16, + rowsums
__global__ __launch_bounds__(256) void k_ent_qk(const unsigned short* __restrict__ proj,
                                                const int* __restrict__ labP,
                                                const int4* __restrict__ qtinfo,
                                                unsigned short* __restrict__ Sbuf,
                                                float* __restrict__ rowsum){
  int qt = blockIdx.y;
  int4 qi = qtinfo[qt];
  int nkt = (qi.y - qi.x) >> 7;
  if ((int)blockIdx.x >= nkt) return;
  int m0 = qt * 128, n0 = qi.x + blockIdx.x * 128;
  __shared__ __align__(16) unsigned short As[128 * 32];
  __shared__ __align__(16) unsigned short Bs[128 * 32];
  __shared__ int lQ[128], lK[128];
  int tid = threadIdx.x, wid = tid >> 6, lane = tid & 63;
  int quad = lane >> 4, l16 = lane & 15;
  int wm = (wid >> 1) * 64, wn = (wid & 1) * 64;
  if (tid < 128) lQ[tid] = labP[m0 + tid] & 0xff;
  else           lK[tid - 128] = labP[n0 + tid - 128] & 0xff;
  f32x4 acc[4][4];
#pragma unroll
  for (int i = 0; i < 4; i++)
#pragma unroll
    for (int j = 0; j < 4; j++) acc[i][j] = f32x4{0.f, 0.f, 0.f, 0.f};

  for (int k0 = 0; k0 < 640; k0 += 32){
    __syncthreads();
#pragma unroll
    for (int u = 0; u < 2; u++){
      int c = tid + u * 256;
      int row = c >> 2, off = (c & 3) * 8;
      gload_lds(&proj[(size_t)(m0 + row) * NPROJ + 1920 + k0 + off], &As[c * 8]);
      gload_lds(&proj[(size_t)(n0 + row) * NPROJ + 2560 + k0 + off], &Bs[c * 8]);
    }
    __syncthreads();
    bf16x8 af[4], bfr[4];
#pragma unroll
    for (int t = 0; t < 4; t++){
      af[t]  = *(const bf16x8*)(&As[(wm + t * 16 + l16) * 32 + quad * 8]);
      bfr[t] = *(const bf16x8*)(&Bs[(wn + t * 16 + l16) * 32 + quad * 8]);
    }
#pragma unroll
    for (int mt = 0; mt < 4; mt++)
#pragma unroll
      for (int nt = 0; nt < 4; nt++)
        acc[mt][nt] = __builtin_amdgcn_mfma_f32_16x16x32_bf16(af[mt], bfr[nt], acc[mt][nt], 0, 0, 0);
  }
  unsigned short* St = Sbuf + ((size_t)(qi.z + blockIdx.x)) * 16384;
#pragma unroll
  for (int mt = 0; mt < 4; mt++)
#pragma unroll
    for (int r = 0; r < 4; r++){
      int lrow = wm + mt * 16 + quad * 4 + r;
      int myq = lQ[lrow];
      float psum = 0.f;
#pragma unroll
      for (int nt = 0; nt < 4; nt++){
        int lcol = wn + nt * 16 + l16;
        float p = (myq == lK[lcol]) ? __expf(acc[mt][nt][r]) : 0.f;
        St[lrow * 128 + lcol] = f2bf(p);
        psum += p;
      }
#pragma unroll
      for (int m = 1; m < 16; m <<= 1) psum += __shfl_xor(psum, m);
      if (l16 == 0) atomicAdd(&rowsum[m0 + lrow], psum);
    }
}

// ---------------- entity E2: attnS = bf16( P·V_e / rowsum + plane0 + plane1 )
__global__ __launch_bounds__(256) void k_ent_pv(const unsigned short* __restrict__ Sbuf,
                                                const unsigned short* __restrict__ veT,
                                                const int4* __restrict__ qtinfo,
                                                const float* __restrict__ rowsum,
                                                const unsigned short* __restrict__ planes,
                                                unsigned short* __restrict__ attnS){
  int qt = blockIdx.y, d0 = blockIdx.x * 128;
  int4 qi = qtinfo[qt];
  int m0 = qt * 128;
  int nk = qi.y - qi.x;
  __shared__ __align__(16) unsigned short As[128 * 32];
  __shared__ __align__(16) unsigned short Bs[128 * 32];
  int tid = threadIdx.x, wid = tid >> 6, lane = tid & 63;
  int quad = lane >> 4, l16 = lane & 15;
  int wm = (wid >> 1) * 64, wn = (wid & 1) * 64;
  f32x4 acc[4][4];
#pragma unroll
  for (int i = 0; i < 4; i++)
#pragma unroll
    for (int j = 0; j < 4; j++) acc[i][j] = f32x4{0.f, 0.f, 0.f, 0.f};

  for (int kk = 0; kk < nk; kk += 32){
    const unsigned short* St = Sbuf + ((size_t)(qi.z + (kk >> 7))) * 16384;
    int kloc = kk & 127;
    __syncthreads();
#pragma unroll
    for (int u = 0; u < 2; u++){
      int c = tid + u * 256;
      int row = c >> 2, off = (c & 3) * 8;
      gload_lds(&St[row * 128 + kloc + off], &As[c * 8]);
      gload_lds(&veT[(size_t)(d0 + row) * S_LEN + qi.x + kk + off], &Bs[c * 8]);
    }
    __syncthreads();
    bf16x8 af[4], bfr[4];
#pragma unroll
    for (int t = 0; t < 4; t++){
      af[t]  = *(const bf16x8*)(&As[(wm + t * 16 + l16) * 32 + quad * 8]);
      bfr[t] = *(const bf16x8*)(&Bs[(wn + t * 16 + l16) * 32 + quad * 8]);
    }
#pragma unroll
    for (int mt = 0; mt < 4; mt++)
#pragma unroll
      for (int nt = 0; nt < 4; nt++)
        acc[mt][nt] = __builtin_amdgcn_mfma_f32_16x16x32_bf16(af[mt], bfr[nt], acc[mt][nt], 0, 0, 0);
  }
#pragma unroll
  for (int mt = 0; mt < 4; mt++)
#pragma unroll
    for (int r = 0; r < 4; r++){
      int row = m0 + wm + mt * 16 + quad * 4 + r;
      float invL = 1.f / rowsum[row];
#pragma unroll
      for (int nt = 0; nt < 4; nt++){
        int col = d0 + wn + nt * 16 + l16;
        size_t idx = (size_t)row * CDIM + col;
        float v = acc[mt][nt][r] * invL + b2f(planes[idx]) + b2f(planes[(size_t)S_LEN * CDIM + idx]);
        attnS[idx] = f2bf(v);
      }
    }
}

extern "C" void kernel_launch(void* const* d_in, const int* in_sizes, int n_in,
                              void* d_out, int out_size, void* d_ws, size_t ws_size,
                              hipStream_t stream){
  const float* hs  = (const float*)d_in[0];
  const int* mask  = (const int*)d_in[1];
  const int* inp   = (const int*)d_in[2];
  char* ws = (char*)d_ws;
  int*            labels  = (int*)(ws + 0);
  int*            boff    = (int*)(ws + 16384);
  int*            cnt     = (int*)(ws + 16640);
  int*            perm    = (int*)(ws + 16896);
  int*            inv     = (int*)(ws + 33280);
  int*            labP    = (int*)(ws + 49664);
  int4*           qtinfo  = (int4*)(ws + 66560);
  float*          rowsum  = (float*)(ws + 67072);
  unsigned short* hsb     = (unsigned short*)(ws + 131072);
  unsigned short* Wall    = (unsigned short*)(ws + 5373952);
  unsigned short* proj    = (unsigned short*)(ws + 13565952);
  unsigned short* vT      = (unsigned short*)(ws + 60751872);
  unsigned short* planes  = (unsigned short*)(ws + 76480512);   // 2 bf16 planes = 10.5 MB
  unsigned short* Sbuf    = (unsigned short*)(ws + 86966272);   // up to 1024 tiles * 32 KB
  unsigned short* attnS   = (unsigned short*)(ws + 120520704);
  unsigned short* Wob     = Wall + 9 * 409600;

  k_labels<<<16, 256, 0, stream>>>(mask, inp, labels);
  k_hist<<<1, 256, 0, stream>>>(labels, boff, cnt);
  k_perm<<<16, 256, 0, stream>>>(labels, boff, cnt, perm, inv, labP);
  k_tiles<<<1, 256, 0, stream>>>(labP, boff, qtinfo, rowsum);
  k_cvt_hs<<<(S_LEN * CDIM / 4 + 255) / 256, 256, 0, stream>>>(hs, hsb, S_LEN * CDIM);
  WPtrs wp;
  for (int i = 0; i < 10; i++) wp.w[i] = (const float*)d_in[3 + i];
  k_cvt_w<<<(10 * 409600 / 4 + 255) / 256, 256, 0, stream>>>(wp, Wall);

  // all 9 projections in one GEMM, rows scattered into bucket-permuted order
  k_gemm<0><<<dim3(45, 32), 256, 0, stream>>>(hsb, Wall, S_LEN, NPROJ, CDIM, NPROJ,
                                              inv, proj, nullptr, nullptr);
  k_transpose_v<<<dim3(64, 10, 3), 256, 0, stream>>>(proj, vT);

  // branches 1+3: z=0 orig (q,k,v), z=1 outside (q_o,k_o,v_o) with im==0 key gate
  k_attn80<<<dim3(32, 8, 2), 256, 0, stream>>>(proj, vT, labP, qtinfo, planes);

  // branch 2 (entity, d=640): GEMM-ified, P materialized bf16 per bucket
  k_ent_qk<<<dim3(32, 32), 256, 0, stream>>>(proj, labP, qtinfo, Sbuf, rowsum);
  k_ent_pv<<<dim3(5, 32), 256, 0, stream>>>(Sbuf, vT + (size_t)1 * CDIM * S_LEN,
                                            qtinfo, rowsum, planes, attnS);

  // out = attnS @ Wo^T + residual, un-permuted via perm in the epilogue
  k_gemm<1><<<dim3(5, 32), 256, 0, stream>>>(attnS, Wob, S_LEN, CDIM, CDIM, CDIM,
                                             perm, nullptr, (float*)d_out, hs);
}